// Round 10
// baseline (69.123 us; speedup 1.0000x reference)
//
#include <hip/hip_runtime.h>

// TauLoss: 1 - mean_c [ sum_{i,j} sign(y[c,i]-y[c,j]) * tanh(p[c,i]-p[c,j]) / (N*(N-1)) ]
//
// Identities:
//   tanh(d*s) = s*tanh(d), s in {-1,0,1}
//   tanh(a-b) = (ta-tb)/(1-ta*tb), r = 1/(1-ta*tb) > 0  -> tanh once per element
//   summand symmetric under i<->j   -> 2 * sum over unordered tri tile-pairs
//   sgn(ld)*n*r == n * copysign(r, ld)   (r>0; one v_bfi_b32 per element,
//                                         replaces and+xor -> -17% VALU/group)
//
// History: R8/R9 (no atomics, plain partials + finalize kernel) ~69us total
// = ~53us immovable harness floor (256MB d_ws poison fill at 40us / 84% HBM
// peak dominates rocprof top-5) + ~16us kernel-side. R9's grid/prefetch
// changes were neutral -> main kernel insensitive to residency now.
// R10: copysign sign-fold (20 cyc / 2-pair group, floor 5.8->4.8us) + 1-wave
// finalize. DECISION PROBE: neutral result here => declare roofline.

typedef float v2f __attribute__((ext_vector_type(2)));

#define TAU_N 1024
#define TAU_C 128
#define TILE  128
#define NTILE (TAU_N / TILE)              // 8
#define NTP   (NTILE * (NTILE + 1) / 2)   // 36 tile-pairs (ti >= tj) per column
#define BPC   6                           // blocks per column
#define JOBS  (NTP / BPC)                 // 6 jobs per block
#define PBLK  (TAU_C * BPC)               // 768 blocks (3 per CU)
#define THR   512                         // 8 waves per block
#define IT    8                           // i-elements per thread

__device__ __constant__ unsigned char c_TI[NTP] = {
    0,1,1,2,2,2,3,3,3,3,4,4,4,4,4,5,5,5,5,5,5,
    6,6,6,6,6,6,6,7,7,7,7,7,7,7,7};
__device__ __constant__ unsigned char c_TJ[NTP] = {
    0,0,1,0,1,2,0,1,2,3,0,1,2,3,4,0,1,2,3,4,5,
    0,1,2,3,4,5,6,0,1,2,3,4,5,6,7};
__device__ __constant__ float c_W[NTP] = {
    0.5f,1,0.5f,1,1,0.5f,1,1,1,0.5f,1,1,1,1,0.5f,1,1,1,1,1,0.5f,
    1,1,1,1,1,1,0.5f,1,1,1,1,1,1,1,0.5f};

// 2 pairs: n = mt-tj; d = 1-mt*tj; ld = ml-lj; acc += n * copysign(rcp(d), ld)
__device__ __forceinline__ v2f tau_group(v2f m2, v2f mly, v2f t2, v2f l2, v2f acc) {
    const v2f one2 = {1.f, 1.f};
    v2f n  = m2 - t2;                                   // pk_sub
    v2f d  = __builtin_elementwise_fma(-m2, t2, one2);  // pk_fma
    v2f ld = mly - l2;                                  // pk_sub
    v2f rs = {__builtin_copysignf(__builtin_amdgcn_rcpf(d.x), ld.x),   // v_bfi
              __builtin_copysignf(__builtin_amdgcn_rcpf(d.y), ld.y)};  // v_bfi
    return __builtin_elementwise_fma(n, rs, acc);       // pk_fma
}

__global__ __launch_bounds__(THR, 6) void tau_tri_kernel(
        const float* __restrict__ pred, const float* __restrict__ y,
        float* __restrict__ partials) {
    __shared__ __align__(16) float ts[TAU_N];   // tanh(p)
    __shared__ __align__(16) float ys[TAU_N];   // y
    __shared__ float wsum[THR / 64];

    const int bx  = blockIdx.x;
    const int tid = threadIdx.x;
    const int c   = bx / BPC;
    const int jb0 = (bx % BPC) * JOBS;

    const float* p = pred + c * TAU_N;
    const float* l = y    + c * TAU_N;

    // Stage column (SoA): 2 elements per thread, one barrier.
    ts[tid]       = tanhf(p[tid]);
    ts[tid + THR] = tanhf(p[tid + THR]);
    ys[tid]       = l[tid];
    ys[tid + THR] = l[tid + THR];
    __syncthreads();

    const float4* t4 = (const float4*)ts;
    const float4* y4 = (const float4*)ys;
    const int ig = tid >> 5;                    // 16 i-groups of IT=8
    const int js = tid & 31;                    // 32 j-slices of 4 j

    // Prefetched LDS vectors for job q: 2x i-t, 2x i-y, 1x j-t, 1x j-y.
    float4 ta, tb, la, lb, tj4, yj4;
    {
        const int ti0 = c_TI[jb0], tj0 = c_TJ[jb0];
        const int ib4 = (ti0 * TILE + ig * IT) >> 2;
        const int jb4 = (tj0 * TILE + js * 4) >> 2;
        ta = t4[ib4]; tb = t4[ib4 + 1];
        la = y4[ib4]; lb = y4[ib4 + 1];
        tj4 = t4[jb4]; yj4 = y4[jb4];
    }

    float acc_tot = 0.f;

#pragma unroll
    for (int q = 0; q < JOBS; ++q) {
        const float w = c_W[jb0 + q];
        const float4 cta = ta, ctb = tb, cla = la, clb = lb;
        const float4 ctj = tj4, cyj = yj4;

        if (q + 1 < JOBS) {                     // prefetch next job's vectors
            const int tin = c_TI[jb0 + q + 1], tjn = c_TJ[jb0 + q + 1];
            const int ib4 = (tin * TILE + ig * IT) >> 2;
            const int jb4 = (tjn * TILE + js * 4) >> 2;
            ta = t4[ib4]; tb = t4[ib4 + 1];
            la = y4[ib4]; lb = y4[ib4 + 1];
            tj4 = t4[jb4]; yj4 = y4[jb4];
        }

        const v2f tA = {ctj.x, ctj.y}, tB = {ctj.z, ctj.w};
        const v2f lA = {cyj.x, cyj.y}, lB = {cyj.z, cyj.w};
        const float mt[IT] = {cta.x, cta.y, cta.z, cta.w, ctb.x, ctb.y, ctb.z, ctb.w};
        const float ml[IT] = {cla.x, cla.y, cla.z, cla.w, clb.x, clb.y, clb.z, clb.w};

        v2f a0 = {0.f,0.f}, a1 = {0.f,0.f}, a2 = {0.f,0.f}, a3 = {0.f,0.f};
#pragma unroll
        for (int a = 0; a < IT; ++a) {
            const v2f m2  = {mt[a], mt[a]};
            const v2f mly = {ml[a], ml[a]};
            if (a & 1) {
                a1 = tau_group(m2, mly, tA, lA, a1);
                a3 = tau_group(m2, mly, tB, lB, a3);
            } else {
                a0 = tau_group(m2, mly, tA, lA, a0);
                a2 = tau_group(m2, mly, tB, lB, a2);
            }
        }
        const v2f asum = (a0 + a1) + (a2 + a3);
        acc_tot = __builtin_fmaf(w, asum.x + asum.y, acc_tot);
    }

    // Wave reduce -> cross-wave LDS -> ONE plain store per block. No atomics.
    for (int off = 32; off >= 1; off >>= 1)
        acc_tot += __shfl_down(acc_tot, off, 64);
    if ((tid & 63) == 0) wsum[tid >> 6] = acc_tot;
    __syncthreads();
    if (tid == 0) {
        float t = 0.f;
#pragma unroll
        for (int w = 0; w < THR / 64; ++w) t += wsum[w];
        partials[bx] = t;
    }
}

// Single-wave finalize: no LDS, no barrier, minimal launch-to-done latency.
__global__ __launch_bounds__(64) void tau_finalize_kernel(
        const float* __restrict__ partials, float* __restrict__ out) {
    const int tid = threadIdx.x;               // 64 threads
    float acc = 0.f;
#pragma unroll
    for (int k = 0; k < PBLK / 64; ++k)        // 12 strided loads each
        acc += partials[tid + k * 64];
    for (int off = 32; off >= 1; off >>= 1)
        acc += __shfl_down(acc, off, 64);
    if (tid == 0) {
        const float scale = 2.0f / ((float)TAU_N * (float)(TAU_N - 1) * (float)TAU_C);
        out[0] = 1.0f - acc * scale;
    }
}

extern "C" void kernel_launch(void* const* d_in, const int* in_sizes, int n_in,
                              void* d_out, int out_size, void* d_ws, size_t ws_size,
                              hipStream_t stream) {
    const float* pred = (const float*)d_in[0];
    const float* y    = (const float*)d_in[1];
    float* out        = (float*)d_out;
    float* partials   = (float*)d_ws;   // PBLK floats; each written exactly once

    tau_tri_kernel<<<PBLK, THR, 0, stream>>>(pred, y, partials);
    tau_finalize_kernel<<<1, 64, 0, stream>>>(partials, out);
}